// Round 4
// baseline (365.472 us; speedup 1.0000x reference)
//
#include <hip/hip_runtime.h>
#include <hip/hip_bf16.h>

#define N_NODES 50000
#define N_EDGES 600000
#define D 128
#define BM 32

typedef __bf16 bf16x8 __attribute__((ext_vector_type(8)));
typedef float f32x4 __attribute__((ext_vector_type(4)));

__device__ __forceinline__ float bits2f(unsigned int u) {
    union { unsigned int i; float f; } t; t.i = u; return t.f;
}
__device__ __forceinline__ unsigned short f2bf(float x) {
    unsigned int u = __builtin_bit_cast(unsigned int, x);
    unsigned int r = (u + 0x7fff + ((u >> 16) & 1)) >> 16;
    return (unsigned short)r;
}

// ---------------------------------------------------------------------------
// prep: fused {cvt_feat | hist | cvt_w} via blockIdx range partition
// ---------------------------------------------------------------------------
#define PREP_CVT_BLOCKS 6250
#define PREP_HIST_BLOCKS 2344
#define PREP_W_BLOCKS 384
__global__ void prep_kernel(const float* __restrict__ feat, unsigned short* __restrict__ g_bf,
                            const int* __restrict__ dst, int* __restrict__ deg,
                            const float* w0, const float* w1, const float* w2,
                            const float* w3, const float* w4, const float* w5,
                            unsigned short* __restrict__ WT) {
    int b = blockIdx.x;
    if (b < PREP_CVT_BLOCKS) {
        int i = b * 256 + threadIdx.x;
        if (i < N_NODES * D / 4) {
            float4 v = *(const float4*)(feat + (size_t)i * 4);
            ushort4 o;
            o.x = f2bf(v.x); o.y = f2bf(v.y); o.z = f2bf(v.z); o.w = f2bf(v.w);
            *(ushort4*)(g_bf + (size_t)i * 4) = o;
        }
    } else if (b < PREP_CVT_BLOCKS + PREP_HIST_BLOCKS) {
        int i = (b - PREP_CVT_BLOCKS) * 256 + threadIdx.x;
        if (i < N_EDGES) atomicAdd(&deg[dst[i]], 1);
    } else {
        int j = (b - PREP_CVT_BLOCKS - PREP_HIST_BLOCKS) * 256 + threadIdx.x; // 0..98303
        int m = j >> 14;
        int e = j & 16383;
        const float* src = m == 0 ? w0 : m == 1 ? w1 : m == 2 ? w2 : m == 3 ? w3 : m == 4 ? w4 : w5;
        int n = e >> 7, k = e & 127;
        WT[m * 16384 + n * 128 + k] = f2bf(src[k * 128 + n]);
    }
}

// ---------------------------------------------------------------------------
// scan_all: single-block exclusive scan of deg -> row_start/cursor/deg_inv
// 1024 threads x 52 contiguous elements (13 uint4) in registers.
// ---------------------------------------------------------------------------
__global__ __launch_bounds__(1024) void scan_all_kernel(const int* __restrict__ deg,
        int* __restrict__ row_start, int* __restrict__ cursor, float* __restrict__ deg_inv) {
    __shared__ int ws[16];
    int t = threadIdx.x;
    int base = t * 52;
    uint4 d[13];
    #pragma unroll
    for (int j = 0; j < 13; ++j) {
        int idx = base + j * 4;
        if (idx + 4 <= N_NODES) {
            d[j] = *(const uint4*)(deg + idx);
        } else {
            unsigned a = (idx < N_NODES) ? (unsigned)deg[idx] : 0u;
            unsigned bb = (idx + 1 < N_NODES) ? (unsigned)deg[idx + 1] : 0u;
            unsigned c = (idx + 2 < N_NODES) ? (unsigned)deg[idx + 2] : 0u;
            unsigned dd = (idx + 3 < N_NODES) ? (unsigned)deg[idx + 3] : 0u;
            d[j] = make_uint4(a, bb, c, dd);
        }
    }
    int s = 0;
    #pragma unroll
    for (int j = 0; j < 13; ++j) s += (int)(d[j].x + d[j].y + d[j].z + d[j].w);
    int lane = t & 63, wid = t >> 6;
    int v = s;
    #pragma unroll
    for (int off = 1; off < 64; off <<= 1) {
        int tmp = __shfl_up(v, off);
        if (lane >= off) v += tmp;
    }
    if (lane == 63) ws[wid] = v;
    __syncthreads();
    if (t == 0) {
        int c = 0;
        #pragma unroll
        for (int j = 0; j < 16; ++j) { int x = ws[j]; ws[j] = c; c += x; }
    }
    __syncthreads();
    int run = v - s + ws[wid];   // exclusive prefix for this thread's chunk
    #pragma unroll
    for (int j = 0; j < 13; ++j) {
        int vals[4] = {(int)d[j].x, (int)d[j].y, (int)d[j].z, (int)d[j].w};
        int rs[4];
        #pragma unroll
        for (int q = 0; q < 4; ++q) { rs[q] = run; run += vals[q]; }
        int idx = base + j * 4;
        if (idx + 4 <= N_NODES) {
            *(int4*)(row_start + idx) = make_int4(rs[0], rs[1], rs[2], rs[3]);
            *(int4*)(cursor + idx) = make_int4(rs[0], rs[1], rs[2], rs[3]);
            float4 di;
            di.x = 1.0f / fmaxf((float)vals[0], 1.0f);
            di.y = 1.0f / fmaxf((float)vals[1], 1.0f);
            di.z = 1.0f / fmaxf((float)vals[2], 1.0f);
            di.w = 1.0f / fmaxf((float)vals[3], 1.0f);
            *(float4*)(deg_inv + idx) = di;
        } else {
            #pragma unroll
            for (int q = 0; q < 4; ++q) {
                if (idx + q < N_NODES) {
                    row_start[idx + q] = rs[q];
                    cursor[idx + q] = rs[q];
                    deg_inv[idx + q] = 1.0f / fmaxf((float)vals[q], 1.0f);
                }
            }
        }
    }
    if (t == 1023) row_start[N_NODES] = N_EDGES;
}

__global__ void fill_kernel(const int* __restrict__ src, const int* __restrict__ dst,
                            int* __restrict__ cursor, int* __restrict__ esrc, int n) {
    int i = blockIdx.x * blockDim.x + threadIdx.x;
    if (i < n) {
        int p = atomicAdd(&cursor[dst[i]], 1);
        esrc[p] = src[i];
    }
}

// ---------------------------------------------------------------------------
// Fused layer: out = relu?( h @ Ws + (deg_inv * A.h) @ Wn + b )
// BM=32 rows/block, 256 threads (4 waves).
//  - gather: 16-lane groups steal nodes from LDS counter, unroll-8 edge loop
//  - phase-0 A frags direct global->VGPR; B frags direct global->VGPR
//  - msum in swizzled bf16 LDS (8 KB), one barrier
// ---------------------------------------------------------------------------
__device__ __forceinline__ void acc_add(float* a, uint4 v) {
    unsigned int wv[4] = {v.x, v.y, v.z, v.w};
    #pragma unroll
    for (int j = 0; j < 4; ++j) {
        a[2*j]   += bits2f(wv[j] << 16);
        a[2*j+1] += bits2f(wv[j] & 0xffff0000u);
    }
}

__global__ __launch_bounds__(256) void layer_kernel(
        const unsigned short* __restrict__ h, const int* __restrict__ row_start,
        const int* __restrict__ esrc, const float* __restrict__ deg_inv,
        const unsigned short* __restrict__ WsT, const unsigned short* __restrict__ WnT,
        const float* __restrict__ bias, void* __restrict__ outp,
        int do_relu, int store_f32) {
    __shared__ char Am[BM * 256];     // msum bf16, swizzled
    __shared__ int rs_s[BM + 1];
    __shared__ float dinv_s[BM];
    __shared__ int ctr_s;
    int tid = threadIdx.x;
    int l = tid & 63, w = tid >> 6;
    int row0 = blockIdx.x * BM;

    // ---- B frags phase 0 (issue early; L2-broadcast) ----
    bf16x8 b0[2][4];
    {
        size_t off = (size_t)(w * 32 + (l & 15)) * D + ((l >> 4) * 8);
        #pragma unroll
        for (int nt = 0; nt < 2; ++nt)
            #pragma unroll
            for (int ks = 0; ks < 4; ++ks)
                b0[nt][ks] = *(const bf16x8*)(WsT + off + nt * 16 * D + ks * 32);
    }
    if (tid <= BM) {
        int node = row0 + tid;
        rs_s[tid] = row_start[node <= N_NODES ? node : N_NODES];
    }
    if (tid < BM) {
        int node = row0 + tid;
        dinv_s[tid] = (node < N_NODES) ? deg_inv[node] : 0.f;
    }
    if (tid == 0) ctr_s = 0;
    __syncthreads();

    // ---- steal-gather: 16 groups x 16 lanes ----
    int l16 = tid & 15;
    const unsigned short* hl = h + l16 * 8;
    for (;;) {
        int n;
        if (l16 == 0) n = atomicAdd(&ctr_s, 1);
        n = __shfl(n, l & 48);
        if (n >= BM) break;
        float acc[8] = {0, 0, 0, 0, 0, 0, 0, 0};
        int s = rs_s[n], e = rs_s[n + 1];
        int k = s;
        for (; k + 8 <= e; k += 8) {
            int i0 = esrc[k],     i1 = esrc[k + 1], i2 = esrc[k + 2], i3 = esrc[k + 3];
            int i4 = esrc[k + 4], i5 = esrc[k + 5], i6 = esrc[k + 6], i7 = esrc[k + 7];
            uint4 v0 = *(const uint4*)(hl + (size_t)i0 * D);
            uint4 v1 = *(const uint4*)(hl + (size_t)i1 * D);
            uint4 v2 = *(const uint4*)(hl + (size_t)i2 * D);
            uint4 v3 = *(const uint4*)(hl + (size_t)i3 * D);
            uint4 v4 = *(const uint4*)(hl + (size_t)i4 * D);
            uint4 v5 = *(const uint4*)(hl + (size_t)i5 * D);
            uint4 v6 = *(const uint4*)(hl + (size_t)i6 * D);
            uint4 v7 = *(const uint4*)(hl + (size_t)i7 * D);
            acc_add(acc, v0); acc_add(acc, v1); acc_add(acc, v2); acc_add(acc, v3);
            acc_add(acc, v4); acc_add(acc, v5); acc_add(acc, v6); acc_add(acc, v7);
        }
        for (; k < e; ++k) {
            uint4 v = *(const uint4*)(hl + (size_t)esrc[k] * D);
            acc_add(acc, v);
        }
        float sc = dinv_s[n];
        unsigned short o[8];
        #pragma unroll
        for (int j = 0; j < 8; ++j) o[j] = f2bf(acc[j] * sc);
        *(uint4*)(Am + n * 256 + ((l16 << 4) ^ ((n & 7) << 4))) = *(uint4*)o;
    }

    // ---- phase-0 A frags direct from global (overlap straggler drain) ----
    bf16x8 a0[2][4];
    #pragma unroll
    for (int mt = 0; mt < 2; ++mt) {
        int r = row0 + mt * 16 + (l & 15);
        if (r >= N_NODES) r = N_NODES - 1;
        const unsigned short* hp = h + (size_t)r * D + ((l >> 4) * 8);
        #pragma unroll
        for (int ks = 0; ks < 4; ++ks)
            a0[mt][ks] = *(const bf16x8*)(hp + ks * 32);
    }
    // ---- B frags phase 1 (also in flight across the barrier wait) ----
    bf16x8 b1[2][4];
    {
        size_t off = (size_t)(w * 32 + (l & 15)) * D + ((l >> 4) * 8);
        #pragma unroll
        for (int nt = 0; nt < 2; ++nt)
            #pragma unroll
            for (int ks = 0; ks < 4; ++ks)
                b1[nt][ks] = *(const bf16x8*)(WnT + off + nt * 16 * D + ks * 32);
    }
    __syncthreads();

    f32x4 acc[2][2];
    #pragma unroll
    for (int mt = 0; mt < 2; ++mt)
        #pragma unroll
        for (int nt = 0; nt < 2; ++nt)
            acc[mt][nt] = (f32x4)0.0f;

    // phase 0: self term
    #pragma unroll
    for (int ks = 0; ks < 4; ++ks)
        #pragma unroll
        for (int mt = 0; mt < 2; ++mt)
            #pragma unroll
            for (int nt = 0; nt < 2; ++nt)
                acc[mt][nt] = __builtin_amdgcn_mfma_f32_16x16x32_bf16(a0[mt][ks], b0[nt][ks], acc[mt][nt], 0, 0, 0);

    // phase 1: neighbor term (A from Am LDS)
    #pragma unroll
    for (int ks = 0; ks < 4; ++ks) {
        int kb = ks * 64 + ((l >> 4) << 4);
        bf16x8 a[2];
        #pragma unroll
        for (int mt = 0; mt < 2; ++mt) {
            int r = mt * 16 + (l & 15);
            a[mt] = *(const bf16x8*)(Am + r * 256 + (kb ^ ((r & 7) << 4)));
        }
        #pragma unroll
        for (int mt = 0; mt < 2; ++mt)
            #pragma unroll
            for (int nt = 0; nt < 2; ++nt)
                acc[mt][nt] = __builtin_amdgcn_mfma_f32_16x16x32_bf16(a[mt], b1[nt][ks], acc[mt][nt], 0, 0, 0);
    }

    // ---- epilogue ----
    #pragma unroll
    for (int nt = 0; nt < 2; ++nt) {
        int col = w * 32 + nt * 16 + (l & 15);
        float bv = bias[col];
        #pragma unroll
        for (int mt = 0; mt < 2; ++mt) {
            #pragma unroll
            for (int r = 0; r < 4; ++r) {
                int grow = row0 + mt * 16 + ((l >> 4) << 2) + r;
                if (grow < N_NODES) {
                    float v = acc[mt][nt][r] + bv;
                    if (do_relu) v = fmaxf(v, 0.f);
                    if (store_f32) ((float*)outp)[(size_t)grow * D + col] = v;
                    else ((unsigned short*)outp)[(size_t)grow * D + col] = f2bf(v);
                }
            }
        }
    }
}

// ---------------------------------------------------------------------------
// Launch
// ---------------------------------------------------------------------------
static inline size_t align_up(size_t x, size_t a) { return (x + a - 1) & ~(a - 1); }

extern "C" void kernel_launch(void* const* d_in, const int* in_sizes, int n_in,
                              void* d_out, int out_size, void* d_ws, size_t ws_size,
                              hipStream_t stream) {
    const float* g_feat = (const float*)d_in[0];
    const int* src = (const int*)d_in[1];
    const int* dst = (const int*)d_in[2];
    const float* Ws1 = (const float*)d_in[3];
    const float* Wn1 = (const float*)d_in[4];
    const float* b1  = (const float*)d_in[5];
    const float* Ws2 = (const float*)d_in[6];
    const float* Wn2 = (const float*)d_in[7];
    const float* b2  = (const float*)d_in[8];
    const float* Ws3 = (const float*)d_in[9];
    const float* Wn3 = (const float*)d_in[10];
    const float* b3  = (const float*)d_in[11];
    float* out = (float*)d_out;

    char* ws = (char*)d_ws;
    int* deg        = (int*)ws;            ws += align_up(N_NODES * 4, 256);
    int* row_start  = (int*)ws;            ws += align_up((N_NODES + 1) * 4, 256);
    int* cursor     = (int*)ws;            ws += align_up(N_NODES * 4, 256);
    float* deg_inv  = (float*)ws;          ws += align_up(N_NODES * 4, 256);
    int* esrc       = (int*)ws;            ws += align_up(N_EDGES * 4, 256);
    unsigned short* g_bf = (unsigned short*)ws;  ws += align_up((size_t)N_NODES * D * 2, 256);
    unsigned short* WT   = (unsigned short*)ws;  ws += align_up(6 * 128 * 128 * 2, 256);
    unsigned short* bufA = (unsigned short*)ws;  ws += align_up((size_t)N_NODES * D * 2, 256);
    unsigned short* bufB = (unsigned short*)ws;  ws += align_up((size_t)N_NODES * D * 2, 256);

    hipMemsetAsync(deg, 0, N_NODES * 4, stream);
    prep_kernel<<<PREP_CVT_BLOCKS + PREP_HIST_BLOCKS + PREP_W_BLOCKS, 256, 0, stream>>>(
        g_feat, g_bf, dst, deg, Ws1, Wn1, Ws2, Wn2, Ws3, Wn3, WT);
    scan_all_kernel<<<1, 1024, 0, stream>>>(deg, row_start, cursor, deg_inv);
    fill_kernel<<<(N_EDGES + 255) / 256, 256, 0, stream>>>(src, dst, cursor, esrc, N_EDGES);

    dim3 grid((N_NODES + BM - 1) / BM);
    const unsigned short *WsT1 = WT, *WnT1 = WT + 16384, *WsT2 = WT + 2*16384,
                         *WnT2 = WT + 3*16384, *WsT3 = WT + 4*16384, *WnT3 = WT + 5*16384;

    layer_kernel<<<grid, 256, 0, stream>>>(g_bf, row_start, esrc, deg_inv, WsT1, WnT1, b1, bufA, 1, 0);
    layer_kernel<<<grid, 256, 0, stream>>>(bufA, row_start, esrc, deg_inv, WsT2, WnT2, b2, bufB, 1, 0);
    layer_kernel<<<grid, 256, 0, stream>>>(bufB, row_start, esrc, deg_inv, WsT3, WnT3, b3, out, 0, 1);
}

// Round 5
// 352.293 us; speedup vs baseline: 1.0374x; 1.0374x over previous
//
#include <hip/hip_runtime.h>
#include <hip/hip_bf16.h>

#define N_NODES 50000
#define N_EDGES 600000
#define D 128

typedef __bf16 bf16x8 __attribute__((ext_vector_type(8)));
typedef float f32x4 __attribute__((ext_vector_type(4)));

__device__ __forceinline__ float bits2f(unsigned int u) {
    union { unsigned int i; float f; } t; t.i = u; return t.f;
}
__device__ __forceinline__ unsigned short f2bf(float x) {
    unsigned int u = __builtin_bit_cast(unsigned int, x);
    unsigned int r = (u + 0x7fff + ((u >> 16) & 1)) >> 16;
    return (unsigned short)r;
}

// ---------------------------------------------------------------------------
// prep: fused {cvt_feat | hist | cvt_w} via blockIdx range partition
// ---------------------------------------------------------------------------
#define PREP_CVT_BLOCKS 6250
#define PREP_HIST_BLOCKS 2344
#define PREP_W_BLOCKS 384
__global__ void prep_kernel(const float* __restrict__ feat, unsigned short* __restrict__ g_bf,
                            const int* __restrict__ dst, int* __restrict__ deg,
                            const float* w0, const float* w1, const float* w2,
                            const float* w3, const float* w4, const float* w5,
                            unsigned short* __restrict__ WT) {
    int b = blockIdx.x;
    if (b < PREP_CVT_BLOCKS) {
        int i = b * 256 + threadIdx.x;
        if (i < N_NODES * D / 4) {
            float4 v = *(const float4*)(feat + (size_t)i * 4);
            ushort4 o;
            o.x = f2bf(v.x); o.y = f2bf(v.y); o.z = f2bf(v.z); o.w = f2bf(v.w);
            *(ushort4*)(g_bf + (size_t)i * 4) = o;
        }
    } else if (b < PREP_CVT_BLOCKS + PREP_HIST_BLOCKS) {
        int i = (b - PREP_CVT_BLOCKS) * 256 + threadIdx.x;
        if (i < N_EDGES) atomicAdd(&deg[dst[i]], 1);
    } else {
        int j = (b - PREP_CVT_BLOCKS - PREP_HIST_BLOCKS) * 256 + threadIdx.x;
        int m = j >> 14;
        int e = j & 16383;
        const float* src = m == 0 ? w0 : m == 1 ? w1 : m == 2 ? w2 : m == 3 ? w3 : m == 4 ? w4 : w5;
        int n = e >> 7, k = e & 127;
        WT[m * 16384 + n * 128 + k] = f2bf(src[k * 128 + n]);
    }
}

// ---------------------------------------------------------------------------
// scan_all: single-block exclusive scan of deg
// ---------------------------------------------------------------------------
__global__ __launch_bounds__(1024) void scan_all_kernel(const int* __restrict__ deg,
        int* __restrict__ row_start, int* __restrict__ cursor, float* __restrict__ deg_inv) {
    __shared__ int ws[16];
    int t = threadIdx.x;
    int base = t * 52;
    uint4 d[13];
    #pragma unroll
    for (int j = 0; j < 13; ++j) {
        int idx = base + j * 4;
        if (idx + 4 <= N_NODES) {
            d[j] = *(const uint4*)(deg + idx);
        } else {
            unsigned a = (idx < N_NODES) ? (unsigned)deg[idx] : 0u;
            unsigned bb = (idx + 1 < N_NODES) ? (unsigned)deg[idx + 1] : 0u;
            unsigned c = (idx + 2 < N_NODES) ? (unsigned)deg[idx + 2] : 0u;
            unsigned dd = (idx + 3 < N_NODES) ? (unsigned)deg[idx + 3] : 0u;
            d[j] = make_uint4(a, bb, c, dd);
        }
    }
    int s = 0;
    #pragma unroll
    for (int j = 0; j < 13; ++j) s += (int)(d[j].x + d[j].y + d[j].z + d[j].w);
    int lane = t & 63, wid = t >> 6;
    int v = s;
    #pragma unroll
    for (int off = 1; off < 64; off <<= 1) {
        int tmp = __shfl_up(v, off);
        if (lane >= off) v += tmp;
    }
    if (lane == 63) ws[wid] = v;
    __syncthreads();
    if (t == 0) {
        int c = 0;
        #pragma unroll
        for (int j = 0; j < 16; ++j) { int x = ws[j]; ws[j] = c; c += x; }
    }
    __syncthreads();
    int run = v - s + ws[wid];
    #pragma unroll
    for (int j = 0; j < 13; ++j) {
        int vals[4] = {(int)d[j].x, (int)d[j].y, (int)d[j].z, (int)d[j].w};
        int rs[4];
        #pragma unroll
        for (int q = 0; q < 4; ++q) { rs[q] = run; run += vals[q]; }
        int idx = base + j * 4;
        if (idx + 4 <= N_NODES) {
            *(int4*)(row_start + idx) = make_int4(rs[0], rs[1], rs[2], rs[3]);
            *(int4*)(cursor + idx) = make_int4(rs[0], rs[1], rs[2], rs[3]);
            float4 di;
            di.x = 1.0f / fmaxf((float)vals[0], 1.0f);
            di.y = 1.0f / fmaxf((float)vals[1], 1.0f);
            di.z = 1.0f / fmaxf((float)vals[2], 1.0f);
            di.w = 1.0f / fmaxf((float)vals[3], 1.0f);
            *(float4*)(deg_inv + idx) = di;
        } else {
            #pragma unroll
            for (int q = 0; q < 4; ++q) {
                if (idx + q < N_NODES) {
                    row_start[idx + q] = rs[q];
                    cursor[idx + q] = rs[q];
                    deg_inv[idx + q] = 1.0f / fmaxf((float)vals[q], 1.0f);
                }
            }
        }
    }
    if (t == 1023) row_start[N_NODES] = N_EDGES;
}

__global__ void fill_kernel(const int* __restrict__ src, const int* __restrict__ dst,
                            int* __restrict__ cursor, int* __restrict__ esrc, int n) {
    int i = blockIdx.x * blockDim.x + threadIdx.x;
    if (i < n) {
        int p = atomicAdd(&cursor[dst[i]], 1);
        esrc[p] = src[i];
    }
}

// ---------------------------------------------------------------------------
// agg: msum[i] = bf16( deg_inv[i] * sum h[esrc] )   (standalone, no barrier)
// 16 lanes/node, 16 nodes per 256-thread block, unroll-8 edge loop.
// ---------------------------------------------------------------------------
__device__ __forceinline__ void acc_add(float* a, uint4 v) {
    unsigned int wv[4] = {v.x, v.y, v.z, v.w};
    #pragma unroll
    for (int j = 0; j < 4; ++j) {
        a[2*j]   += bits2f(wv[j] << 16);
        a[2*j+1] += bits2f(wv[j] & 0xffff0000u);
    }
}

__global__ __launch_bounds__(256) void agg_kernel(
        const unsigned short* __restrict__ h, const int* __restrict__ row_start,
        const int* __restrict__ esrc, const float* __restrict__ deg_inv,
        unsigned short* __restrict__ msum) {
    int node = blockIdx.x * 16 + (threadIdx.x >> 4);
    if (node >= N_NODES) return;
    int l16 = threadIdx.x & 15;
    int s = row_start[node], e = row_start[node + 1];
    const unsigned short* hl = h + l16 * 8;
    float acc[8] = {0, 0, 0, 0, 0, 0, 0, 0};
    int k = s;
    for (; k + 8 <= e; k += 8) {
        int i0 = esrc[k],     i1 = esrc[k + 1], i2 = esrc[k + 2], i3 = esrc[k + 3];
        int i4 = esrc[k + 4], i5 = esrc[k + 5], i6 = esrc[k + 6], i7 = esrc[k + 7];
        uint4 v0 = *(const uint4*)(hl + (size_t)i0 * D);
        uint4 v1 = *(const uint4*)(hl + (size_t)i1 * D);
        uint4 v2 = *(const uint4*)(hl + (size_t)i2 * D);
        uint4 v3 = *(const uint4*)(hl + (size_t)i3 * D);
        uint4 v4 = *(const uint4*)(hl + (size_t)i4 * D);
        uint4 v5 = *(const uint4*)(hl + (size_t)i5 * D);
        uint4 v6 = *(const uint4*)(hl + (size_t)i6 * D);
        uint4 v7 = *(const uint4*)(hl + (size_t)i7 * D);
        acc_add(acc, v0); acc_add(acc, v1); acc_add(acc, v2); acc_add(acc, v3);
        acc_add(acc, v4); acc_add(acc, v5); acc_add(acc, v6); acc_add(acc, v7);
    }
    for (; k < e; ++k) {
        uint4 v = *(const uint4*)(hl + (size_t)esrc[k] * D);
        acc_add(acc, v);
    }
    float di = deg_inv[node];
    unsigned short o[8];
    #pragma unroll
    for (int j = 0; j < 8; ++j) o[j] = f2bf(acc[j] * di);
    *(uint4*)(msum + (size_t)node * D + l16 * 8) = *(uint4*)o;
}

// ---------------------------------------------------------------------------
// GEMM: out = relu?( h @ Ws + msum @ Wn + b )   BM=32, 256 thr (4 waves)
// No operand LDS: A frags (h, msum) and B frags (W) global->VGPR.
// LDS only for epilogue transpose -> coalesced row stores.
// ---------------------------------------------------------------------------
#define TS_LD 132
__global__ __launch_bounds__(256) void gemm_kernel(
        const unsigned short* __restrict__ h, const unsigned short* __restrict__ msum,
        const unsigned short* __restrict__ WsT, const unsigned short* __restrict__ WnT,
        const float* __restrict__ bias, void* __restrict__ outp,
        int do_relu, int store_f32) {
    __shared__ float ts[32 * TS_LD];   // 16.9 KB
    int tid = threadIdx.x;
    int l = tid & 63, w = tid >> 6;
    int row0 = blockIdx.x * 32;

    // B fragments: W broadcast (L2-hot)
    bf16x8 b0[2][4], b1[2][4];
    {
        size_t off = (size_t)(w * 32 + (l & 15)) * D + ((l >> 4) * 8);
        #pragma unroll
        for (int nt = 0; nt < 2; ++nt)
            #pragma unroll
            for (int ks = 0; ks < 4; ++ks) {
                b0[nt][ks] = *(const bf16x8*)(WsT + off + nt * 16 * D + ks * 32);
                b1[nt][ks] = *(const bf16x8*)(WnT + off + nt * 16 * D + ks * 32);
            }
    }
    // A fragments: h rows and msum rows, direct
    bf16x8 a0[2][4], am[2][4];
    #pragma unroll
    for (int mt = 0; mt < 2; ++mt) {
        int r = row0 + mt * 16 + (l & 15);
        if (r >= N_NODES) r = N_NODES - 1;
        const unsigned short* hp = h + (size_t)r * D + ((l >> 4) * 8);
        const unsigned short* mp = msum + (size_t)r * D + ((l >> 4) * 8);
        #pragma unroll
        for (int ks = 0; ks < 4; ++ks) {
            a0[mt][ks] = *(const bf16x8*)(hp + ks * 32);
            am[mt][ks] = *(const bf16x8*)(mp + ks * 32);
        }
    }

    f32x4 acc[2][2];
    #pragma unroll
    for (int mt = 0; mt < 2; ++mt)
        #pragma unroll
        for (int nt = 0; nt < 2; ++nt)
            acc[mt][nt] = (f32x4)0.0f;

    #pragma unroll
    for (int ks = 0; ks < 4; ++ks)
        #pragma unroll
        for (int mt = 0; mt < 2; ++mt)
            #pragma unroll
            for (int nt = 0; nt < 2; ++nt)
                acc[mt][nt] = __builtin_amdgcn_mfma_f32_16x16x32_bf16(a0[mt][ks], b0[nt][ks], acc[mt][nt], 0, 0, 0);
    #pragma unroll
    for (int ks = 0; ks < 4; ++ks)
        #pragma unroll
        for (int mt = 0; mt < 2; ++mt)
            #pragma unroll
            for (int nt = 0; nt < 2; ++nt)
                acc[mt][nt] = __builtin_amdgcn_mfma_f32_16x16x32_bf16(am[mt][ks], b1[nt][ks], acc[mt][nt], 0, 0, 0);

    // bias + relu, write fragments into LDS transpose buffer
    #pragma unroll
    for (int nt = 0; nt < 2; ++nt) {
        int col = w * 32 + nt * 16 + (l & 15);
        float bv = bias[col];
        #pragma unroll
        for (int mt = 0; mt < 2; ++mt) {
            #pragma unroll
            for (int r = 0; r < 4; ++r) {
                int lrow = mt * 16 + ((l >> 4) << 2) + r;
                float v = acc[mt][nt][r] + bv;
                if (do_relu) v = fmaxf(v, 0.f);
                ts[lrow * TS_LD + col] = v;
            }
        }
    }
    __syncthreads();

    // coalesced stores
    if (store_f32) {
        float* out = (float*)outp;
        #pragma unroll
        for (int i = 0; i < 4; ++i) {
            int c = tid + i * 256;              // 0..1023
            int lrow = c >> 5, seg = c & 31;    // 32 float4 per row
            int grow = row0 + lrow;
            if (grow < N_NODES) {
                const float* p = &ts[lrow * TS_LD + seg * 4];
                float4 v = make_float4(p[0], p[1], p[2], p[3]);
                *(float4*)(out + (size_t)grow * D + seg * 4) = v;
            }
        }
    } else {
        unsigned short* out = (unsigned short*)outp;
        #pragma unroll
        for (int i = 0; i < 2; ++i) {
            int c = tid + i * 256;              // 0..511
            int lrow = c >> 4, seg = c & 15;    // 16 x (8 bf16) per row
            int grow = row0 + lrow;
            if (grow < N_NODES) {
                const float* p = &ts[lrow * TS_LD + seg * 8];
                unsigned short o[8];
                #pragma unroll
                for (int j = 0; j < 8; ++j) o[j] = f2bf(p[j]);
                *(uint4*)(out + (size_t)grow * D + seg * 8) = *(uint4*)o;
            }
        }
    }
}

// ---------------------------------------------------------------------------
// Launch
// ---------------------------------------------------------------------------
static inline size_t align_up(size_t x, size_t a) { return (x + a - 1) & ~(a - 1); }

extern "C" void kernel_launch(void* const* d_in, const int* in_sizes, int n_in,
                              void* d_out, int out_size, void* d_ws, size_t ws_size,
                              hipStream_t stream) {
    const float* g_feat = (const float*)d_in[0];
    const int* src = (const int*)d_in[1];
    const int* dst = (const int*)d_in[2];
    const float* Ws1 = (const float*)d_in[3];
    const float* Wn1 = (const float*)d_in[4];
    const float* b1  = (const float*)d_in[5];
    const float* Ws2 = (const float*)d_in[6];
    const float* Wn2 = (const float*)d_in[7];
    const float* b2  = (const float*)d_in[8];
    const float* Ws3 = (const float*)d_in[9];
    const float* Wn3 = (const float*)d_in[10];
    const float* b3  = (const float*)d_in[11];
    float* out = (float*)d_out;

    char* ws = (char*)d_ws;
    int* deg        = (int*)ws;            ws += align_up(N_NODES * 4, 256);
    int* row_start  = (int*)ws;            ws += align_up((N_NODES + 1) * 4, 256);
    int* cursor     = (int*)ws;            ws += align_up(N_NODES * 4, 256);
    float* deg_inv  = (float*)ws;          ws += align_up(N_NODES * 4, 256);
    int* esrc       = (int*)ws;            ws += align_up(N_EDGES * 4, 256);
    unsigned short* g_bf = (unsigned short*)ws;  ws += align_up((size_t)N_NODES * D * 2, 256);
    unsigned short* WT   = (unsigned short*)ws;  ws += align_up(6 * 128 * 128 * 2, 256);
    unsigned short* bufA = (unsigned short*)ws;  ws += align_up((size_t)N_NODES * D * 2, 256);
    unsigned short* bufB = (unsigned short*)ws;  ws += align_up((size_t)N_NODES * D * 2, 256);
    unsigned short* bufM = (unsigned short*)ws;  ws += align_up((size_t)N_NODES * D * 2, 256);

    hipMemsetAsync(deg, 0, N_NODES * 4, stream);
    prep_kernel<<<PREP_CVT_BLOCKS + PREP_HIST_BLOCKS + PREP_W_BLOCKS, 256, 0, stream>>>(
        g_feat, g_bf, dst, deg, Ws1, Wn1, Ws2, Wn2, Ws3, Wn3, WT);
    scan_all_kernel<<<1, 1024, 0, stream>>>(deg, row_start, cursor, deg_inv);
    fill_kernel<<<(N_EDGES + 255) / 256, 256, 0, stream>>>(src, dst, cursor, esrc, N_EDGES);

    dim3 agg_grid((N_NODES + 15) / 16);
    dim3 gemm_grid((N_NODES + 31) / 32);
    const unsigned short *WsT1 = WT, *WnT1 = WT + 16384, *WsT2 = WT + 2*16384,
                         *WnT2 = WT + 3*16384, *WsT3 = WT + 4*16384, *WnT3 = WT + 5*16384;

    // layer 1
    agg_kernel<<<agg_grid, 256, 0, stream>>>(g_bf, row_start, esrc, deg_inv, bufM);
    gemm_kernel<<<gemm_grid, 256, 0, stream>>>(g_bf, bufM, WsT1, WnT1, b1, bufA, 1, 0);
    // layer 2
    agg_kernel<<<agg_grid, 256, 0, stream>>>(bufA, row_start, esrc, deg_inv, bufM);
    gemm_kernel<<<gemm_grid, 256, 0, stream>>>(bufA, bufM, WsT2, WnT2, b2, bufB, 1, 0);
    // layer 3
    agg_kernel<<<agg_grid, 256, 0, stream>>>(bufB, row_start, esrc, deg_inv, bufM);
    gemm_kernel<<<gemm_grid, 256, 0, stream>>>(bufB, bufM, WsT3, WnT3, b3, out, 0, 1);
}

// Round 6
// 337.493 us; speedup vs baseline: 1.0829x; 1.0439x over previous
//
#include <hip/hip_runtime.h>
#include <hip/hip_bf16.h>

#define N_NODES 50000
#define N_EDGES 600000
#define D 128

typedef __bf16 bf16x8 __attribute__((ext_vector_type(8)));
typedef float f32x4 __attribute__((ext_vector_type(4)));

__device__ __forceinline__ float bits2f(unsigned int u) {
    union { unsigned int i; float f; } t; t.i = u; return t.f;
}
__device__ __forceinline__ unsigned short f2bf(float x) {
    unsigned int u = __builtin_bit_cast(unsigned int, x);
    unsigned int r = (u + 0x7fff + ((u >> 16) & 1)) >> 16;
    return (unsigned short)r;
}

// ---------------------------------------------------------------------------
// prep: fused {cvt_feat | hist | cvt_w} via blockIdx range partition
// ---------------------------------------------------------------------------
#define PREP_CVT_BLOCKS 6250
#define PREP_HIST_BLOCKS 2344
#define PREP_W_BLOCKS 384
__global__ void prep_kernel(const float* __restrict__ feat, unsigned short* __restrict__ g_bf,
                            const int* __restrict__ dst, int* __restrict__ deg,
                            const float* w0, const float* w1, const float* w2,
                            const float* w3, const float* w4, const float* w5,
                            unsigned short* __restrict__ WT) {
    int b = blockIdx.x;
    if (b < PREP_CVT_BLOCKS) {
        int i = b * 256 + threadIdx.x;
        if (i < N_NODES * D / 4) {
            float4 v = *(const float4*)(feat + (size_t)i * 4);
            ushort4 o;
            o.x = f2bf(v.x); o.y = f2bf(v.y); o.z = f2bf(v.z); o.w = f2bf(v.w);
            *(ushort4*)(g_bf + (size_t)i * 4) = o;
        }
    } else if (b < PREP_CVT_BLOCKS + PREP_HIST_BLOCKS) {
        int i = (b - PREP_CVT_BLOCKS) * 256 + threadIdx.x;
        if (i < N_EDGES) atomicAdd(&deg[dst[i]], 1);
    } else {
        int j = (b - PREP_CVT_BLOCKS - PREP_HIST_BLOCKS) * 256 + threadIdx.x;
        int m = j >> 14;
        int e = j & 16383;
        const float* src = m == 0 ? w0 : m == 1 ? w1 : m == 2 ? w2 : m == 3 ? w3 : m == 4 ? w4 : w5;
        int n = e >> 7, k = e & 127;
        WT[m * 16384 + n * 128 + k] = f2bf(src[k * 128 + n]);
    }
}

// ---------------------------------------------------------------------------
// scan_all: single-block exclusive scan of deg
// ---------------------------------------------------------------------------
__global__ __launch_bounds__(1024) void scan_all_kernel(const int* __restrict__ deg,
        int* __restrict__ row_start, int* __restrict__ cursor, float* __restrict__ deg_inv) {
    __shared__ int ws[16];
    int t = threadIdx.x;
    int base = t * 52;
    uint4 d[13];
    #pragma unroll
    for (int j = 0; j < 13; ++j) {
        int idx = base + j * 4;
        if (idx + 4 <= N_NODES) {
            d[j] = *(const uint4*)(deg + idx);
        } else {
            unsigned a = (idx < N_NODES) ? (unsigned)deg[idx] : 0u;
            unsigned bb = (idx + 1 < N_NODES) ? (unsigned)deg[idx + 1] : 0u;
            unsigned c = (idx + 2 < N_NODES) ? (unsigned)deg[idx + 2] : 0u;
            unsigned dd = (idx + 3 < N_NODES) ? (unsigned)deg[idx + 3] : 0u;
            d[j] = make_uint4(a, bb, c, dd);
        }
    }
    int s = 0;
    #pragma unroll
    for (int j = 0; j < 13; ++j) s += (int)(d[j].x + d[j].y + d[j].z + d[j].w);
    int lane = t & 63, wid = t >> 6;
    int v = s;
    #pragma unroll
    for (int off = 1; off < 64; off <<= 1) {
        int tmp = __shfl_up(v, off);
        if (lane >= off) v += tmp;
    }
    if (lane == 63) ws[wid] = v;
    __syncthreads();
    if (t == 0) {
        int c = 0;
        #pragma unroll
        for (int j = 0; j < 16; ++j) { int x = ws[j]; ws[j] = c; c += x; }
    }
    __syncthreads();
    int run = v - s + ws[wid];
    #pragma unroll
    for (int j = 0; j < 13; ++j) {
        int vals[4] = {(int)d[j].x, (int)d[j].y, (int)d[j].z, (int)d[j].w};
        int rs[4];
        #pragma unroll
        for (int q = 0; q < 4; ++q) { rs[q] = run; run += vals[q]; }
        int idx = base + j * 4;
        if (idx + 4 <= N_NODES) {
            *(int4*)(row_start + idx) = make_int4(rs[0], rs[1], rs[2], rs[3]);
            *(int4*)(cursor + idx) = make_int4(rs[0], rs[1], rs[2], rs[3]);
            float4 di;
            di.x = 1.0f / fmaxf((float)vals[0], 1.0f);
            di.y = 1.0f / fmaxf((float)vals[1], 1.0f);
            di.z = 1.0f / fmaxf((float)vals[2], 1.0f);
            di.w = 1.0f / fmaxf((float)vals[3], 1.0f);
            *(float4*)(deg_inv + idx) = di;
        } else {
            #pragma unroll
            for (int q = 0; q < 4; ++q) {
                if (idx + q < N_NODES) {
                    row_start[idx + q] = rs[q];
                    cursor[idx + q] = rs[q];
                    deg_inv[idx + q] = 1.0f / fmaxf((float)vals[q], 1.0f);
                }
            }
        }
    }
    if (t == 1023) row_start[N_NODES] = N_EDGES;
}

__global__ void fill_kernel(const int* __restrict__ src, const int* __restrict__ dst,
                            int* __restrict__ cursor, int* __restrict__ esrc, int n) {
    int i = blockIdx.x * blockDim.x + threadIdx.x;
    if (i < n) {
        int p = atomicAdd(&cursor[dst[i]], 1);
        esrc[p] = src[i];
    }
}

// ---------------------------------------------------------------------------
// agg: msum[i] = bf16( deg_inv[i] * sum h[esrc] )
// 16 lanes/node, 16 nodes per 256-thread block.
// Branchless masked rounds of 8: every round issues 8 independent row loads
// (indices clamped to e-1; duplicates hit L1), accumulate is predicated.
// Critical path = ceil(deg/8) parallel rounds — no serial tail.
// ---------------------------------------------------------------------------
__device__ __forceinline__ void acc_add(float* a, uint4 v) {
    unsigned int wv[4] = {v.x, v.y, v.z, v.w};
    #pragma unroll
    for (int j = 0; j < 4; ++j) {
        a[2*j]   += bits2f(wv[j] << 16);
        a[2*j+1] += bits2f(wv[j] & 0xffff0000u);
    }
}

__global__ __launch_bounds__(256) void agg_kernel(
        const unsigned short* __restrict__ h, const int* __restrict__ row_start,
        const int* __restrict__ esrc, const float* __restrict__ deg_inv,
        unsigned short* __restrict__ msum) {
    int node = blockIdx.x * 16 + (threadIdx.x >> 4);
    if (node >= N_NODES) return;
    int l16 = threadIdx.x & 15;
    int s = row_start[node], e = row_start[node + 1];
    const unsigned short* hl = h + l16 * 8;
    float acc[8] = {0, 0, 0, 0, 0, 0, 0, 0};
    for (int k = s; k < e; k += 8) {
        int idx[8];
        #pragma unroll
        for (int j = 0; j < 8; ++j) {
            int kk = k + j;
            idx[j] = esrc[kk < e ? kk : e - 1];
        }
        uint4 v[8];
        #pragma unroll
        for (int j = 0; j < 8; ++j)
            v[j] = *(const uint4*)(hl + (size_t)idx[j] * D);
        #pragma unroll
        for (int j = 0; j < 8; ++j)
            if (k + j < e) acc_add(acc, v[j]);
    }
    float di = deg_inv[node];
    unsigned short o[8];
    #pragma unroll
    for (int j = 0; j < 8; ++j) o[j] = f2bf(acc[j] * di);
    *(uint4*)(msum + (size_t)node * D + l16 * 8) = *(uint4*)o;
}

// ---------------------------------------------------------------------------
// GEMM: out = relu?( h @ Ws + msum @ Wn + b )   BM=32, 256 thr (4 waves)
// No operand LDS: A frags (h, msum) and B frags (W) global->VGPR.
// LDS only for epilogue transpose -> coalesced row stores.
// ---------------------------------------------------------------------------
#define TS_LD 132
__global__ __launch_bounds__(256) void gemm_kernel(
        const unsigned short* __restrict__ h, const unsigned short* __restrict__ msum,
        const unsigned short* __restrict__ WsT, const unsigned short* __restrict__ WnT,
        const float* __restrict__ bias, void* __restrict__ outp,
        int do_relu, int store_f32) {
    __shared__ float ts[32 * TS_LD];   // 16.9 KB
    int tid = threadIdx.x;
    int l = tid & 63, w = tid >> 6;
    int row0 = blockIdx.x * 32;

    // B fragments: W broadcast (L2-hot)
    bf16x8 b0[2][4], b1[2][4];
    {
        size_t off = (size_t)(w * 32 + (l & 15)) * D + ((l >> 4) * 8);
        #pragma unroll
        for (int nt = 0; nt < 2; ++nt)
            #pragma unroll
            for (int ks = 0; ks < 4; ++ks) {
                b0[nt][ks] = *(const bf16x8*)(WsT + off + nt * 16 * D + ks * 32);
                b1[nt][ks] = *(const bf16x8*)(WnT + off + nt * 16 * D + ks * 32);
            }
    }
    // A fragments: h rows and msum rows, direct
    bf16x8 a0[2][4], am[2][4];
    #pragma unroll
    for (int mt = 0; mt < 2; ++mt) {
        int r = row0 + mt * 16 + (l & 15);
        if (r >= N_NODES) r = N_NODES - 1;
        const unsigned short* hp = h + (size_t)r * D + ((l >> 4) * 8);
        const unsigned short* mp = msum + (size_t)r * D + ((l >> 4) * 8);
        #pragma unroll
        for (int ks = 0; ks < 4; ++ks) {
            a0[mt][ks] = *(const bf16x8*)(hp + ks * 32);
            am[mt][ks] = *(const bf16x8*)(mp + ks * 32);
        }
    }

    f32x4 acc[2][2];
    #pragma unroll
    for (int mt = 0; mt < 2; ++mt)
        #pragma unroll
        for (int nt = 0; nt < 2; ++nt)
            acc[mt][nt] = (f32x4)0.0f;

    #pragma unroll
    for (int ks = 0; ks < 4; ++ks)
        #pragma unroll
        for (int mt = 0; mt < 2; ++mt)
            #pragma unroll
            for (int nt = 0; nt < 2; ++nt)
                acc[mt][nt] = __builtin_amdgcn_mfma_f32_16x16x32_bf16(a0[mt][ks], b0[nt][ks], acc[mt][nt], 0, 0, 0);
    #pragma unroll
    for (int ks = 0; ks < 4; ++ks)
        #pragma unroll
        for (int mt = 0; mt < 2; ++mt)
            #pragma unroll
            for (int nt = 0; nt < 2; ++nt)
                acc[mt][nt] = __builtin_amdgcn_mfma_f32_16x16x32_bf16(am[mt][ks], b1[nt][ks], acc[mt][nt], 0, 0, 0);

    // bias + relu, write fragments into LDS transpose buffer
    #pragma unroll
    for (int nt = 0; nt < 2; ++nt) {
        int col = w * 32 + nt * 16 + (l & 15);
        float bv = bias[col];
        #pragma unroll
        for (int mt = 0; mt < 2; ++mt) {
            #pragma unroll
            for (int r = 0; r < 4; ++r) {
                int lrow = mt * 16 + ((l >> 4) << 2) + r;
                float v = acc[mt][nt][r] + bv;
                if (do_relu) v = fmaxf(v, 0.f);
                ts[lrow * TS_LD + col] = v;
            }
        }
    }
    __syncthreads();

    // coalesced stores
    if (store_f32) {
        float* out = (float*)outp;
        #pragma unroll
        for (int i = 0; i < 4; ++i) {
            int c = tid + i * 256;              // 0..1023
            int lrow = c >> 5, seg = c & 31;    // 32 float4 per row
            int grow = row0 + lrow;
            if (grow < N_NODES) {
                const float* p = &ts[lrow * TS_LD + seg * 4];
                float4 v = make_float4(p[0], p[1], p[2], p[3]);
                *(float4*)(out + (size_t)grow * D + seg * 4) = v;
            }
        }
    } else {
        unsigned short* out = (unsigned short*)outp;
        #pragma unroll
        for (int i = 0; i < 2; ++i) {
            int c = tid + i * 256;              // 0..511
            int lrow = c >> 4, seg = c & 15;    // 16 x (8 bf16) per row
            int grow = row0 + lrow;
            if (grow < N_NODES) {
                const float* p = &ts[lrow * TS_LD + seg * 8];
                unsigned short o[8];
                #pragma unroll
                for (int j = 0; j < 8; ++j) o[j] = f2bf(p[j]);
                *(uint4*)(out + (size_t)grow * D + seg * 8) = *(uint4*)o;
            }
        }
    }
}

// ---------------------------------------------------------------------------
// Launch
// ---------------------------------------------------------------------------
static inline size_t align_up(size_t x, size_t a) { return (x + a - 1) & ~(a - 1); }

extern "C" void kernel_launch(void* const* d_in, const int* in_sizes, int n_in,
                              void* d_out, int out_size, void* d_ws, size_t ws_size,
                              hipStream_t stream) {
    const float* g_feat = (const float*)d_in[0];
    const int* src = (const int*)d_in[1];
    const int* dst = (const int*)d_in[2];
    const float* Ws1 = (const float*)d_in[3];
    const float* Wn1 = (const float*)d_in[4];
    const float* b1  = (const float*)d_in[5];
    const float* Ws2 = (const float*)d_in[6];
    const float* Wn2 = (const float*)d_in[7];
    const float* b2  = (const float*)d_in[8];
    const float* Ws3 = (const float*)d_in[9];
    const float* Wn3 = (const float*)d_in[10];
    const float* b3  = (const float*)d_in[11];
    float* out = (float*)d_out;

    char* ws = (char*)d_ws;
    int* deg        = (int*)ws;            ws += align_up(N_NODES * 4, 256);
    int* row_start  = (int*)ws;            ws += align_up((N_NODES + 1) * 4, 256);
    int* cursor     = (int*)ws;            ws += align_up(N_NODES * 4, 256);
    float* deg_inv  = (float*)ws;          ws += align_up(N_NODES * 4, 256);
    int* esrc       = (int*)ws;            ws += align_up(N_EDGES * 4, 256);
    unsigned short* g_bf = (unsigned short*)ws;  ws += align_up((size_t)N_NODES * D * 2, 256);
    unsigned short* WT   = (unsigned short*)ws;  ws += align_up(6 * 128 * 128 * 2, 256);
    unsigned short* bufA = (unsigned short*)ws;  ws += align_up((size_t)N_NODES * D * 2, 256);
    unsigned short* bufB = (unsigned short*)ws;  ws += align_up((size_t)N_NODES * D * 2, 256);
    unsigned short* bufM = (unsigned short*)ws;  ws += align_up((size_t)N_NODES * D * 2, 256);

    hipMemsetAsync(deg, 0, N_NODES * 4, stream);
    prep_kernel<<<PREP_CVT_BLOCKS + PREP_HIST_BLOCKS + PREP_W_BLOCKS, 256, 0, stream>>>(
        g_feat, g_bf, dst, deg, Ws1, Wn1, Ws2, Wn2, Ws3, Wn3, WT);
    scan_all_kernel<<<1, 1024, 0, stream>>>(deg, row_start, cursor, deg_inv);
    fill_kernel<<<(N_EDGES + 255) / 256, 256, 0, stream>>>(src, dst, cursor, esrc, N_EDGES);

    dim3 agg_grid((N_NODES + 15) / 16);
    dim3 gemm_grid((N_NODES + 31) / 32);
    const unsigned short *WsT1 = WT, *WnT1 = WT + 16384, *WsT2 = WT + 2*16384,
                         *WnT2 = WT + 3*16384, *WsT3 = WT + 4*16384, *WnT3 = WT + 5*16384;

    // layer 1
    agg_kernel<<<agg_grid, 256, 0, stream>>>(g_bf, row_start, esrc, deg_inv, bufM);
    gemm_kernel<<<gemm_grid, 256, 0, stream>>>(g_bf, bufM, WsT1, WnT1, b1, bufA, 1, 0);
    // layer 2
    agg_kernel<<<agg_grid, 256, 0, stream>>>(bufA, row_start, esrc, deg_inv, bufM);
    gemm_kernel<<<gemm_grid, 256, 0, stream>>>(bufA, bufM, WsT2, WnT2, b2, bufB, 1, 0);
    // layer 3
    agg_kernel<<<agg_grid, 256, 0, stream>>>(bufB, row_start, esrc, deg_inv, bufM);
    gemm_kernel<<<gemm_grid, 256, 0, stream>>>(bufB, bufM, WsT3, WnT3, b3, out, 0, 1);
}